// Round 2
// baseline (86.799 us; speedup 1.0000x reference)
//
#include <hip/hip_runtime.h>
#include <math.h>

#define BATCH 8
#define H 256
#define W 256
#define NPIX (BATCH * H * W)
#define NBLK2 1024  // K2: 8 img x 4 colstrips x 32 rowstrips

__device__ __forceinline__ float bce_logits(float p, float t) {
    return fmaxf(p, 0.0f) - p * t + log1pf(expf(-fabsf(p)));
}

// K1: row EDT via ballot masks; stores d as ushort (d in [0,255] or 10000=INF).
// Layout d16[b*65536 + r*256 + w]. Block = (image, row-quad), thread = column.
// Also zeroes the K2 ticket counter (stream order makes it visible to K2).
__global__ void __launch_bounds__(256) row_edt(const float* __restrict__ target,
                                               unsigned short* __restrict__ d16,
                                               unsigned int* __restrict__ counter) {
    if (blockIdx.x == 0 && threadIdx.x == 0) *counter = 0u;

    __shared__ unsigned long long mlds[4][4];
    const int tid = threadIdx.x;
    const int v = tid >> 6, l = tid & 63;
    const float* imgr = target + (size_t)blockIdx.x * 4 * W;

    #pragma unroll
    for (int j = 0; j < 4; ++j) {
        float t = imgr[j * W + tid];
        unsigned long long m = __ballot(t == 0.0f);
        if (l == 0) mlds[j][v] = m;
    }
    __syncthreads();

    const int p = tid;                     // column
    #pragma unroll
    for (int j = 0; j < 4; ++j) {
        unsigned long long mw[4] = {mlds[j][0], mlds[j][1], mlds[j][2], mlds[j][3]};
        int best = 1 << 20;
        #pragma unroll
        for (int w = 0; w < 4; ++w) {
            const int rel = p - (w << 6);
            const unsigned long long m = mw[w];
            unsigned long long mlo = (rel < 0)  ? 0ull
                                   : (rel >= 63) ? m : (m & ((2ull << rel) - 1ull));
            unsigned long long mhi = (rel <= 0) ? m
                                   : (rel > 63)  ? 0ull : (m & (~0ull << rel));
            if (mlo) best = min(best, rel - (63 - __builtin_clzll(mlo)));
            if (mhi) best = min(best, __builtin_ctzll(mhi) - rel);
        }
        d16[(size_t)blockIdx.x * 4 * W + j * W + tid] =
            (best > 255) ? (unsigned short)10000 : (unsigned short)best;  // INF per ref
    }
}

// K2: column envelope (pipelined prologue + bit-exact early-exit tail) + BCE,
// plus last-block final reduction (replaces the old K3 dispatch).
__global__ void __launch_bounds__(256) envelope_bce(
        const unsigned short* __restrict__ d16, const float* __restrict__ pred,
        float* __restrict__ pmx, float* __restrict__ psb, float* __restrict__ psdb,
        unsigned int* __restrict__ counter, float* __restrict__ out) {
    __shared__ float red[3][4];
    __shared__ int islast;
    const int tid = threadIdx.x;
    const int wv = tid >> 6, l = tid & 63;
    const int b  = blockIdx.x >> 7;               // image (128 blocks each)
    const int cs = (blockIdx.x >> 5) & 3;         // column strip (64 cols)
    const int rs = blockIdx.x & 31;               // row strip (8 rows)
    const int c  = (cs << 6) + l;                 // this lane's column
    const int i0 = (rs << 3) + (wv << 1);         // rows i0, i0+1

    // pred loads issued early (consumed at the end)
    const size_t po = ((size_t)(b * H + i0)) * W + c;
    float p0 = pred[po], p1 = pred[po + W];

    const unsigned short* gcol = d16 + (size_t)b * H * W + c;

    float acc0 = 3.0e38f, acc1 = 3.0e38f;
    // Prologue: P steps each way, unconditional (clamped + OOB sentinel).
    // Includes k=i0 (s=1, ed0=0) and k=i0+1 (s=0, ed1=0) -> acc==0 iff t==0.
    const int P = 10;
    #pragma unroll
    for (int s = 0; s < P; ++s) {
        const int kd = i0 + 1 - s;
        const int ku = i0 + 2 + s;
        float dd = (float)gcol[(size_t)max(kd, 0) * W];
        float du = (float)gcol[(size_t)min(ku, 255) * W];
        float gd = dd * dd, gu = du * du;         // exact squares
        if (kd < 0)   gd = 3.0e38f;
        if (ku > 255) gu = 3.0e38f;
        const float ed0 = (float)(s - 1), ed1 = (float)s;       // r - kd
        const float eu0 = (float)(s + 2), eu1 = (float)(s + 1); // ku - r
        acc0 = fminf(acc0, fminf(fmaf(ed0, ed0, gd), fmaf(eu0, eu0, gu)));
        acc1 = fminf(acc1, fminf(fmaf(ed1, ed1, gd), fmaf(eu1, eu1, gu)));
    }

    // Tail: exact early-exit two-pointer scan (rarely runs).
    int kd = i0 + 1 - P, ku = i0 + 2 + P;
    float fd0 = (float)(i0 - kd);
    float fu0 = (float)(ku - i0);
    for (;;) {
        float maxacc = fmaxf(acc0, acc1);
        float dn = (float)(i0 - kd);
        float up = (float)(ku - (i0 + 1));
        bool alive = (kd >= 0 && dn * dn <= maxacc) || (ku <= 255 && up * up <= maxacc);
        if (!__any(alive)) break;
        if (kd >= 0) {
            float dv = (float)gcol[(size_t)kd * W];
            float g = dv * dv;
            acc0 = fminf(acc0, fmaf(fd0, fd0, g));
            float fd1 = fd0 + 1.0f;
            acc1 = fminf(acc1, fmaf(fd1, fd1, g));
        }
        if (ku <= 255) {
            float dv = (float)gcol[(size_t)ku * W];
            float g = dv * dv;
            float fu1 = fu0 - 1.0f;
            acc0 = fminf(acc0, fmaf(fu0, fu0, g));
            acc1 = fminf(acc1, fmaf(fu1, fu1, g));
        }
        --kd; ++ku; fd0 += 1.0f; fu0 += 1.0f;
    }

    // Epilogue: fused BCE (t derived from acc) + per-block partials.
    float t0 = (acc0 == 0.0f) ? 0.0f : 1.0f;      // exact: d2==0 <=> target==0
    float t1 = (acc1 == 0.0f) ? 0.0f : 1.0f;
    float mx = fmaxf(acc0, acc1);
    float b0 = bce_logits(p0, t0), b1 = bce_logits(p1, t1);
    float sb  = b0 + b1;
    float sdb = sqrtf(acc0) * b0 + sqrtf(acc1) * b1;

    #pragma unroll
    for (int o = 32; o > 0; o >>= 1) {
        mx  = fmaxf(mx, __shfl_down(mx, o, 64));
        sb  += __shfl_down(sb, o, 64);
        sdb += __shfl_down(sdb, o, 64);
    }
    if (l == 0) { red[0][wv] = mx; red[1][wv] = sb; red[2][wv] = sdb; }
    __syncthreads();
    if (tid == 0) {
        pmx [blockIdx.x] = fmaxf(fmaxf(red[0][0], red[0][1]), fmaxf(red[0][2], red[0][3]));
        psb [blockIdx.x] = (red[1][0] + red[1][1]) + (red[1][2] + red[1][3]);
        psdb[blockIdx.x] = (red[2][0] + red[2][1]) + (red[2][2] + red[2][3]);
        __threadfence();                           // release partials device-wide
        unsigned int ticket = atomicAdd(counter, 1u);
        islast = (ticket == NBLK2 - 1) ? 1 : 0;
    }
    __syncthreads();
    if (!islast) return;

    // ---- Last block: former K3, bit-identical arithmetic (256 threads). ----
    __threadfence();                               // acquire all blocks' partials
    const volatile float* vmx  = pmx;
    const volatile float* vsb  = psb;
    const volatile float* vsdb = psdb;
    const int img = tid >> 5, j = tid & 31;        // 8 images x 32 threads
    float fmx = 0.0f, fsb = 0.0f, fsdb = 0.0f;
    #pragma unroll
    for (int q = 0; q < 4; ++q) {
        const int e = (img << 7) + j + (q << 5);
        fmx  = fmaxf(fmx, vmx[e]);
        fsb  += vsb[e];
        fsdb += vsdb[e];
    }
    #pragma unroll
    for (int o = 16; o > 0; o >>= 1) {             // width-32 groups stay per-image
        fmx  = fmaxf(fmx, __shfl_down(fmx, o, 32));
        fsb  += __shfl_down(fsb, o, 32);
        fsdb += __shfl_down(fsdb, o, 32);
    }
    __shared__ float cimg[8], simg[8];
    if (j == 0) {
        cimg[img] = fsdb / (sqrtf(fmx) + 1e-7f);   // sqrt commutes with max
        simg[img] = fsb;
    }
    __syncthreads();
    if (tid == 0) {
        float tot = 0.0f;
        #pragma unroll
        for (int i = 0; i < 8; ++i) tot += simg[i] + cimg[i];
        out[0] = tot * (1.0f / (float)NPIX);
    }
}

extern "C" void kernel_launch(void* const* d_in, const int* in_sizes, int n_in,
                              void* d_out, int out_size, void* d_ws, size_t ws_size,
                              hipStream_t stream) {
    const float* pred   = (const float*)d_in[0];
    const float* target = (const float*)d_in[1];

    unsigned short* d16 = (unsigned short*)d_ws;                  // 1 MB
    float* pmx  = (float*)((char*)d_ws + (size_t)NPIX * sizeof(unsigned short));
    float* psb  = pmx + NBLK2;
    float* psdb = psb + NBLK2;
    unsigned int* counter = (unsigned int*)(psdb + NBLK2);

    row_edt<<<BATCH * 64, 256, 0, stream>>>(target, d16, counter);   // 512 blocks
    envelope_bce<<<NBLK2, 256, 0, stream>>>(d16, pred, pmx, psb, psdb,
                                            counter, (float*)d_out);
}

// Round 3
// 77.024 us; speedup vs baseline: 1.1269x; 1.1269x over previous
//
#include <hip/hip_runtime.h>
#include <math.h>

#define BATCH 8
#define H 256
#define W 256
#define NPIX (BATCH * H * W)
#define NBLK2 1024  // 8 img x 4 colstrips x 32 rowstrips

__device__ __forceinline__ float bce_logits(float p, float t) {
    return fmaxf(p, 0.0f) - p * t + log1pf(expf(-fabsf(p)));
}

// Nearest-zero distance along a row at column p, from 4x64b zero-masks.
__device__ __forceinline__ int rowdist_scan(const unsigned long long mw[4], int p) {
    int best = 1 << 20;
    #pragma unroll
    for (int w = 0; w < 4; ++w) {
        const int rel = p - (w << 6);
        const unsigned long long m = mw[w];
        unsigned long long mlo = (rel < 0)  ? 0ull
                               : (rel >= 63) ? m : (m & ((2ull << rel) - 1ull));
        unsigned long long mhi = (rel <= 0) ? m
                               : (rel > 63)  ? 0ull : (m & (~0ull << rel));
        if (mlo) best = min(best, rel - (63 - __builtin_clzll(mlo)));
        if (mhi) best = min(best, __builtin_ctzll(mhi) - rel);
    }
    return best;
}

// Fused row-EDT + column envelope + BCE. Block structure identical to the
// proven K2 (256 thr, 1024 blocks); row-EDT is computed per block for a
// 32-row window via ballot masks (no global d16, no K1 dispatch).
// Exact fallback: if the early-exit tail needs rows outside the window
// (never on this data), the block rebuilds full-image masks and scans on
// the fly. No atomics, no threadfence (R2 lesson: those cost ~21 us).
__global__ void __launch_bounds__(256) fused_edt_bce(
        const float* __restrict__ target, const float* __restrict__ pred,
        float* __restrict__ pmx, float* __restrict__ psb, float* __restrict__ psdb) {
    __shared__ unsigned long long msk[256][4];     // window: j-indexed; fallback: row-indexed
    __shared__ unsigned short dtile[32][64];       // row-EDT for window rows x 64 cols
    __shared__ float red[3][4];

    const int tid = threadIdx.x;
    const int wv = tid >> 6, l = tid & 63;
    const int b  = blockIdx.x >> 7;               // image (128 blocks each)
    const int cs = (blockIdx.x >> 5) & 3;         // column strip (64 cols)
    const int rs = blockIdx.x & 31;               // row strip (8 rows)
    const int c  = (cs << 6) + l;                 // this lane's column
    const int i0 = (rs << 3) + (wv << 1);         // rows i0, i0+1

    const int win0 = (rs << 3) - 12;              // window rows [win0, win0+31]
    const int wlo = max(win0, 0), whi = min(win0 + 31, 255);

    // pred loads issued early (consumed at the end)
    const size_t po = ((size_t)(b * H + i0)) * W + c;
    float p0 = pred[po], p1 = pred[po + W];

    const float* img = target + (size_t)b * (H * W);

    // ---- Phase A: zero-masks for the 32-row window (4 chunks x 64b per row).
    // Wave wv: chunks q = wv*32+i -> window row j=q>>2 (8 rows/wave), coalesced.
    #pragma unroll 8
    for (int i = 0; i < 32; ++i) {
        const int q = (wv << 5) + i;
        const int j = q >> 2, ch = q & 3;
        const int row = min(max(win0 + j, 0), 255);
        const float t = img[row * W + (ch << 6) + l];
        const unsigned long long m = __ballot(t == 0.0f);
        if (l == 0) msk[j][ch] = m;
    }
    __syncthreads();

    // ---- Phase B: row-EDT for own column, 8 window rows per thread.
    #pragma unroll
    for (int i = 0; i < 8; ++i) {
        const int j = wv + (i << 2);
        const unsigned long long mw[4] = {msk[j][0], msk[j][1], msk[j][2], msk[j][3]};
        const int best = rowdist_scan(mw, c);
        dtile[j][l] = (best > 255) ? (unsigned short)10000 : (unsigned short)best;
    }
    __syncthreads();

    // ---- Phase C: column envelope (bit-identical math to proven K2).
    float acc0 = 3.0e38f, acc1 = 3.0e38f;
    const int P = 10;
    #pragma unroll
    for (int s = 0; s < P; ++s) {
        const int kd = i0 + 1 - s;
        const int ku = i0 + 2 + s;
        const int rd = max(kd, 0), ru = min(ku, 255);
        float dd = (float)dtile[rd - win0][l];
        float du = (float)dtile[ru - win0][l];
        float gd = dd * dd, gu = du * du;             // exact squares
        if (kd < 0)   gd = 3.0e38f;
        if (ku > 255) gu = 3.0e38f;
        const float ed0 = (float)(s - 1), ed1 = (float)s;       // r - kd
        const float eu0 = (float)(s + 2), eu1 = (float)(s + 1); // ku - r
        acc0 = fminf(acc0, fminf(fmaf(ed0, ed0, gd), fmaf(eu0, eu0, gu)));
        acc1 = fminf(acc1, fminf(fmaf(ed1, ed1, gd), fmaf(eu1, eu1, gu)));
    }

    // In-window early-exit tail (wave-uniform kd/ku; violation -> fallback).
    int kd = i0 + 1 - P, ku = i0 + 2 + P;
    float fd0 = (float)(i0 - kd);
    float fu0 = (float)(ku - i0);
    bool beyond = false;
    for (;;) {
        float maxacc = fmaxf(acc0, acc1);
        float dn = (float)(i0 - kd);
        float up = (float)(ku - (i0 + 1));
        bool alive = (kd >= 0 && dn * dn <= maxacc) || (ku <= 255 && up * up <= maxacc);
        if (!__any(alive)) break;
        if ((kd >= 0 && kd < wlo) || (ku <= 255 && ku > whi)) { beyond = true; break; }
        if (kd >= 0) {
            float dv = (float)dtile[kd - win0][l];
            float g = dv * dv;
            acc0 = fminf(acc0, fmaf(fd0, fd0, g));
            float fd1 = fd0 + 1.0f;
            acc1 = fminf(acc1, fmaf(fd1, fd1, g));
        }
        if (ku <= 255) {
            float dv = (float)dtile[ku - win0][l];
            float g = dv * dv;
            float fu1 = fu0 - 1.0f;
            acc0 = fminf(acc0, fmaf(fu0, fu0, g));
            acc1 = fminf(acc1, fmaf(fu1, fu1, g));
        }
        --kd; ++ku; fd0 += 1.0f; fu0 += 1.0f;
    }

    // Exact fallback (block-uniform; never triggers on this data): rebuild
    // full-image masks, then continue the two-pointer scan on the fly.
    const unsigned need = (unsigned)__syncthreads_count(beyond ? 1 : 0);
    if (need) {
        #pragma unroll 4
        for (int i = 0; i < 256; ++i) {
            const int q = (wv << 8) + i;
            const int row = q >> 2, ch = q & 3;
            const float t = img[row * W + (ch << 6) + l];
            const unsigned long long m = __ballot(t == 0.0f);
            if (l == 0) msk[row][ch] = m;
        }
        __syncthreads();
        for (;;) {
            float maxacc = fmaxf(acc0, acc1);
            float dn = (float)(i0 - kd);
            float up = (float)(ku - (i0 + 1));
            bool alive = (kd >= 0 && dn * dn <= maxacc) || (ku <= 255 && up * up <= maxacc);
            if (!__any(alive)) break;
            if (kd >= 0) {
                const unsigned long long mw[4] = {msk[kd][0], msk[kd][1], msk[kd][2], msk[kd][3]};
                const int best = rowdist_scan(mw, c);
                float dv = (best > 255) ? 10000.0f : (float)best;
                float g = dv * dv;
                acc0 = fminf(acc0, fmaf(fd0, fd0, g));
                float fd1 = fd0 + 1.0f;
                acc1 = fminf(acc1, fmaf(fd1, fd1, g));
            }
            if (ku <= 255) {
                const unsigned long long mw[4] = {msk[ku][0], msk[ku][1], msk[ku][2], msk[ku][3]};
                const int best = rowdist_scan(mw, c);
                float dv = (best > 255) ? 10000.0f : (float)best;
                float g = dv * dv;
                float fu1 = fu0 - 1.0f;
                acc0 = fminf(acc0, fmaf(fu0, fu0, g));
                acc1 = fminf(acc1, fmaf(fu1, fu1, g));
            }
            --kd; ++ku; fd0 += 1.0f; fu0 += 1.0f;
        }
    }

    // ---- Epilogue: fused BCE (t derived from acc) + per-block partials.
    float t0 = (acc0 == 0.0f) ? 0.0f : 1.0f;      // exact: d2==0 <=> target==0
    float t1 = (acc1 == 0.0f) ? 0.0f : 1.0f;
    float mx = fmaxf(acc0, acc1);
    float b0 = bce_logits(p0, t0), b1 = bce_logits(p1, t1);
    float sb  = b0 + b1;
    float sdb = sqrtf(acc0) * b0 + sqrtf(acc1) * b1;

    #pragma unroll
    for (int o = 32; o > 0; o >>= 1) {
        mx  = fmaxf(mx, __shfl_down(mx, o, 64));
        sb  += __shfl_down(sb, o, 64);
        sdb += __shfl_down(sdb, o, 64);
    }
    if (l == 0) { red[0][wv] = mx; red[1][wv] = sb; red[2][wv] = sdb; }
    __syncthreads();
    if (tid == 0) {
        pmx [blockIdx.x] = fmaxf(fmaxf(red[0][0], red[0][1]), fmaxf(red[0][2], red[0][3]));
        psb [blockIdx.x] = (red[1][0] + red[1][1]) + (red[1][2] + red[1][3]);
        psdb[blockIdx.x] = (red[2][0] + red[2][1]) + (red[2][2] + red[2][3]);
    }
}

// K3: 1024 partials -> scalar. Images are contiguous 128-block runs.
__global__ void final_reduce(const float* __restrict__ pmx, const float* __restrict__ psb,
                             const float* __restrict__ psdb, float* __restrict__ out) {
    const int tid = threadIdx.x;
    const int img = tid >> 5, j = tid & 31;        // 8 images x 32 threads
    float mx = 0.0f, sb = 0.0f, sdb = 0.0f;
    #pragma unroll
    for (int q = 0; q < 4; ++q) {
        const int e = (img << 7) + j + (q << 5);
        mx  = fmaxf(mx, pmx[e]);
        sb  += psb[e];
        sdb += psdb[e];
    }
    #pragma unroll
    for (int o = 16; o > 0; o >>= 1) {             // width-32 groups stay per-image
        mx  = fmaxf(mx, __shfl_down(mx, o, 32));
        sb  += __shfl_down(sb, o, 32);
        sdb += __shfl_down(sdb, o, 32);
    }
    __shared__ float cimg[8], simg[8];
    if (j == 0) {
        cimg[img] = sdb / (sqrtf(mx) + 1e-7f);     // sqrt commutes with max
        simg[img] = sb;
    }
    __syncthreads();
    if (tid == 0) {
        float tot = 0.0f;
        #pragma unroll
        for (int i = 0; i < 8; ++i) tot += simg[i] + cimg[i];
        out[0] = tot * (1.0f / (float)NPIX);
    }
}

extern "C" void kernel_launch(void* const* d_in, const int* in_sizes, int n_in,
                              void* d_out, int out_size, void* d_ws, size_t ws_size,
                              hipStream_t stream) {
    const float* pred   = (const float*)d_in[0];
    const float* target = (const float*)d_in[1];

    float* pmx  = (float*)d_ws;
    float* psb  = pmx + NBLK2;
    float* psdb = psb + NBLK2;

    fused_edt_bce<<<NBLK2, 256, 0, stream>>>(target, pred, pmx, psb, psdb);
    final_reduce<<<1, 256, 0, stream>>>(pmx, psb, psdb, (float*)d_out);
}

// Round 4
// 66.002 us; speedup vs baseline: 1.3151x; 1.1670x over previous
//
#include <hip/hip_runtime.h>
#include <math.h>

#define BATCH 8
#define H 256
#define W 256
#define NPIX (BATCH * H * W)
#define NBLK2 1024  // K2: 8 img x 4 colstrips x 32 rowstrips

__device__ __forceinline__ float bce_logits(float p, float t) {
    return fmaxf(p, 0.0f) - p * t + log1pf(expf(-fabsf(p)));
}

// K1: row EDT via ballot masks; stores d as ushort (d in [0,255] or 10000=INF).
// Layout d16[b*65536 + r*256 + w]. Block = (image, row-quad), thread = column.
__global__ void __launch_bounds__(256) row_edt(const float* __restrict__ target,
                                               unsigned short* __restrict__ d16) {
    __shared__ unsigned long long mlds[4][4];
    const int tid = threadIdx.x;
    const int v = tid >> 6, l = tid & 63;
    const float* imgr = target + (size_t)blockIdx.x * 4 * W;

    #pragma unroll
    for (int j = 0; j < 4; ++j) {
        float t = imgr[j * W + tid];
        unsigned long long m = __ballot(t == 0.0f);
        if (l == 0) mlds[j][v] = m;
    }
    __syncthreads();

    const int p = tid;                     // column
    #pragma unroll
    for (int j = 0; j < 4; ++j) {
        unsigned long long mw[4] = {mlds[j][0], mlds[j][1], mlds[j][2], mlds[j][3]};
        int best = 1 << 20;
        #pragma unroll
        for (int w = 0; w < 4; ++w) {
            const int rel = p - (w << 6);
            const unsigned long long m = mw[w];
            unsigned long long mlo = (rel < 0)  ? 0ull
                                   : (rel >= 63) ? m : (m & ((2ull << rel) - 1ull));
            unsigned long long mhi = (rel <= 0) ? m
                                   : (rel > 63)  ? 0ull : (m & (~0ull << rel));
            if (mlo) best = min(best, rel - (63 - __builtin_clzll(mlo)));
            if (mhi) best = min(best, __builtin_ctzll(mhi) - rel);
        }
        d16[(size_t)blockIdx.x * 4 * W + j * W + tid] =
            (best > 255) ? (unsigned short)10000 : (unsigned short)best;  // INF per ref
    }
}

// K2: column envelope (pipelined prologue + bit-exact early-exit tail) + BCE.
// Lane = column; thread owns rows i0, i0+1. g2 = ((float)d)^2 computed inline
// (exact: integers < 2^24; 1e4^2 = 1e8 exact). target is NOT read: t = (d2>0),
// exact because acc includes the k=i candidate (acc==0 <=> pixel is zero).
__global__ void __launch_bounds__(256) envelope_bce(
        const unsigned short* __restrict__ d16, const float* __restrict__ pred,
        float* __restrict__ pmx, float* __restrict__ psb, float* __restrict__ psdb) {
    __shared__ float red[3][4];
    const int tid = threadIdx.x;
    const int wv = tid >> 6, l = tid & 63;
    const int b  = blockIdx.x >> 7;               // image (128 blocks each)
    const int cs = (blockIdx.x >> 5) & 3;         // column strip (64 cols)
    const int rs = blockIdx.x & 31;               // row strip (8 rows)
    const int c  = (cs << 6) + l;                 // this lane's column
    const int i0 = (rs << 3) + (wv << 1);         // rows i0, i0+1

    // pred loads issued early (consumed at the end)
    const size_t po = ((size_t)(b * H + i0)) * W + c;
    float p0 = pred[po], p1 = pred[po + W];

    const unsigned short* gcol = d16 + (size_t)b * H * W + c;

    float acc0 = 3.0e38f, acc1 = 3.0e38f;
    // Prologue: P steps each way, unconditional (clamped + OOB sentinel).
    // Includes k=i0 (s=1, ed0=0) and k=i0+1 (s=0, ed1=0) -> acc==0 iff t==0.
    const int P = 10;
    #pragma unroll
    for (int s = 0; s < P; ++s) {
        const int kd = i0 + 1 - s;
        const int ku = i0 + 2 + s;
        float dd = (float)gcol[(size_t)max(kd, 0) * W];
        float du = (float)gcol[(size_t)min(ku, 255) * W];
        float gd = dd * dd, gu = du * du;         // exact squares
        if (kd < 0)   gd = 3.0e38f;
        if (ku > 255) gu = 3.0e38f;
        const float ed0 = (float)(s - 1), ed1 = (float)s;       // r - kd
        const float eu0 = (float)(s + 2), eu1 = (float)(s + 1); // ku - r
        acc0 = fminf(acc0, fminf(fmaf(ed0, ed0, gd), fmaf(eu0, eu0, gu)));
        acc1 = fminf(acc1, fminf(fmaf(ed1, ed1, gd), fmaf(eu1, eu1, gu)));
    }

    // Tail: exact early-exit two-pointer scan (rarely runs).
    int kd = i0 + 1 - P, ku = i0 + 2 + P;
    float fd0 = (float)(i0 - kd);
    float fu0 = (float)(ku - i0);
    for (;;) {
        float maxacc = fmaxf(acc0, acc1);
        float dn = (float)(i0 - kd);
        float up = (float)(ku - (i0 + 1));
        bool alive = (kd >= 0 && dn * dn <= maxacc) || (ku <= 255 && up * up <= maxacc);
        if (!__any(alive)) break;
        if (kd >= 0) {
            float dv = (float)gcol[(size_t)kd * W];
            float g = dv * dv;
            acc0 = fminf(acc0, fmaf(fd0, fd0, g));
            float fd1 = fd0 + 1.0f;
            acc1 = fminf(acc1, fmaf(fd1, fd1, g));
        }
        if (ku <= 255) {
            float dv = (float)gcol[(size_t)ku * W];
            float g = dv * dv;
            float fu1 = fu0 - 1.0f;
            acc0 = fminf(acc0, fmaf(fu0, fu0, g));
            acc1 = fminf(acc1, fmaf(fu1, fu1, g));
        }
        --kd; ++ku; fd0 += 1.0f; fu0 += 1.0f;
    }

    // Epilogue: fused BCE (t derived from acc) + per-block partials.
    float t0 = (acc0 == 0.0f) ? 0.0f : 1.0f;      // exact: d2==0 <=> target==0
    float t1 = (acc1 == 0.0f) ? 0.0f : 1.0f;
    float mx = fmaxf(acc0, acc1);
    float b0 = bce_logits(p0, t0), b1 = bce_logits(p1, t1);
    float sb  = b0 + b1;
    float sdb = sqrtf(acc0) * b0 + sqrtf(acc1) * b1;

    #pragma unroll
    for (int o = 32; o > 0; o >>= 1) {
        mx  = fmaxf(mx, __shfl_down(mx, o, 64));
        sb  += __shfl_down(sb, o, 64);
        sdb += __shfl_down(sdb, o, 64);
    }
    if (l == 0) { red[0][wv] = mx; red[1][wv] = sb; red[2][wv] = sdb; }
    __syncthreads();
    if (tid == 0) {
        pmx [blockIdx.x] = fmaxf(fmaxf(red[0][0], red[0][1]), fmaxf(red[0][2], red[0][3]));
        psb [blockIdx.x] = (red[1][0] + red[1][1]) + (red[1][2] + red[1][3]);
        psdb[blockIdx.x] = (red[2][0] + red[2][1]) + (red[2][2] + red[2][3]);
    }
}

// K3: 1024 partials -> scalar. Images are contiguous 128-block runs.
__global__ void final_reduce(const float* __restrict__ pmx, const float* __restrict__ psb,
                             const float* __restrict__ psdb, float* __restrict__ out) {
    const int tid = threadIdx.x;
    const int img = tid >> 5, j = tid & 31;        // 8 images x 32 threads
    float mx = 0.0f, sb = 0.0f, sdb = 0.0f;
    #pragma unroll
    for (int q = 0; q < 4; ++q) {
        const int e = (img << 7) + j + (q << 5);
        mx  = fmaxf(mx, pmx[e]);
        sb  += psb[e];
        sdb += psdb[e];
    }
    #pragma unroll
    for (int o = 16; o > 0; o >>= 1) {             // width-32 groups stay per-image
        mx  = fmaxf(mx, __shfl_down(mx, o, 32));
        sb  += __shfl_down(sb, o, 32);
        sdb += __shfl_down(sdb, o, 32);
    }
    __shared__ float cimg[8], simg[8];
    if (j == 0) {
        cimg[img] = sdb / (sqrtf(mx) + 1e-7f);     // sqrt commutes with max
        simg[img] = sb;
    }
    __syncthreads();
    if (tid == 0) {
        float tot = 0.0f;
        #pragma unroll
        for (int i = 0; i < 8; ++i) tot += simg[i] + cimg[i];
        out[0] = tot * (1.0f / (float)NPIX);
    }
}

extern "C" void kernel_launch(void* const* d_in, const int* in_sizes, int n_in,
                              void* d_out, int out_size, void* d_ws, size_t ws_size,
                              hipStream_t stream) {
    const float* pred   = (const float*)d_in[0];
    const float* target = (const float*)d_in[1];

    unsigned short* d16 = (unsigned short*)d_ws;                  // 1 MB
    float* pmx  = (float*)((char*)d_ws + (size_t)NPIX * sizeof(unsigned short));
    float* psb  = pmx + NBLK2;
    float* psdb = psb + NBLK2;

    row_edt<<<BATCH * 64, 256, 0, stream>>>(target, d16);         // 512 blocks
    envelope_bce<<<NBLK2, 256, 0, stream>>>(d16, pred, pmx, psb, psdb);
    final_reduce<<<1, 256, 0, stream>>>(pmx, psb, psdb, (float*)d_out);
}